// Round 4
// baseline (136.318 us; speedup 1.0000x reference)
//
#include <hip/hip_runtime.h>
#include <hip/hip_bf16.h>

#define NND 51
#define FIN 4
#define PDIM 137
#define EMB 32
#define EE 408
#define BD 32
#define PC 5
#define NCH 28            // ceil(137/5)
#define NE (NND*EMB)      // 1632

// ws layout (floats)
#define WS_AMP   0        // Ahat compact [d][s] stride 51, padded to 2604
#define WS_PROBS 2608     // 137 (+pad)
#define WS_WU    2752     // [2][4][32] folded W*U
#define WS_BEFF  3008     // [2][32]  folded b*U + b2
#define WS_CNT   3072     // 32 int counters (last-block detection)
#define WS_H     3104     // [B][N][EMB] accumulator (exact-zeroed by setup)

// fused-kernel shared offsets (floats), single union'd buffer
#define OFF_AS   0        // 2604
#define OFF_XS   2604     // 1020 : x[pp][n][f], f contiguous (float4 per (pp,n))
#define OFF_AG   3624     // 1020 : agg[pp][d][f] (float4 per (pp,d))
#define OFF_WU   4644     // 256
#define OFF_BE   4900     // 64
#define OFF_PR   4964     // 8
#define OFF_FLAG 4972     // 1 (int)
#define SM_N     4976
// head phase reuses the same buffer (main phase fully done by then):
#define H_HS     0        // 1632
#define H_W1     1632     // 1024
#define H_B1     2656     // 32
#define H_W2     2688     // 32
#define H_W3     2720     // 51
#define H_WS     2772     // 4

// grid(8). Block 0: Ahat + softmax + folded gate mats. Blocks 1-7: zero h+cnt.
__global__ __launch_bounds__(256) void setup_kernel(
    const int* __restrict__ ei, const float* __restrict__ att,
    const float* __restrict__ Wz, const float* __restrict__ bz,
    const float* __restrict__ Wh, const float* __restrict__ bh,
    const float* __restrict__ Uz, const float* __restrict__ bz2,
    const float* __restrict__ Uh, const float* __restrict__ bh2,
    float* __restrict__ ws)
{
    int t = threadIdx.x, blk = blockIdx.x;
    if (blk > 0) {   // zero cnt[32] + h[BD*NE] (16B-aligned, 13064 float4s)
        float4* dst = (float4*)(ws + WS_CNT);
        const int n4 = (32 + BD * NE) / 4;
        float4 z = make_float4(0.f, 0.f, 0.f, 0.f);
        for (int i = (blk - 1) * 256 + t; i < n4; i += 7 * 256) dst[i] = z;
        return;
    }
    __shared__ float deg[NND], dinv[NND];
    __shared__ float Am[2604];
    __shared__ float Us[2][EMB * EMB];
    __shared__ float Ws2[2][FIN * EMB];
    __shared__ float atts[PDIM];
    __shared__ float inv_sum;
    for (int i = t; i < 2604; i += 256) Am[i] = 0.0f;
    if (t < NND) deg[t] = 0.0f;
    for (int i = t; i < EMB * EMB; i += 256) { Us[0][i] = Uz[i]; Us[1][i] = Uh[i]; }
    if (t < FIN * EMB) { Ws2[0][t] = Wz[t]; Ws2[1][t] = Wh[t]; }
    if (t < PDIM) atts[t] = att[t];
    __syncthreads();
    for (int e = t; e < EE; e += 256) atomicAdd(&deg[ei[EE + e]], 1.0f);
    __syncthreads();
    if (t < NND) dinv[t] = rsqrtf(deg[t] + 1.0f);   // +1 self loop
    __syncthreads();
    for (int e = t; e < EE; e += 256) {
        int s = ei[e], d = ei[EE + e];
        atomicAdd(&Am[d * NND + s], dinv[s] * dinv[d]);
    }
    {   // wu[g][f][e]: t encodes (g,f,e), 2*4*32 = 256
        int g = t >> 7, f = (t >> 5) & 3, e = t & 31;
        float a = 0.0f;
        for (int k = 0; k < EMB; k++) a += Ws2[g][f * EMB + k] * Us[g][k * EMB + e];
        ws[WS_WU + t] = a;
    }
    if (t < 64) {   // beff[g][e] = b*U + b2
        int g = t >> 5, e = t & 31;
        const float* bb = g ? bh : bz;
        const float* b2 = g ? bh2 : bz2;
        float a = b2[e];
        for (int k = 0; k < EMB; k++) a += bb[k] * Us[g][k * EMB + e];
        ws[WS_BEFF + t] = a;
    }
    __syncthreads();
    if (t < NND) Am[t * 52] += dinv[t] * dinv[t];   // diag: t*51+t
    if (t == 0) {
        float m = -1e30f;
        for (int p = 0; p < PDIM; p++) m = fmaxf(m, atts[p]);
        float s = 0.0f;
        for (int p = 0; p < PDIM; p++) { float v = __expf(atts[p] - m); atts[p] = v; s += v; }
        inv_sum = 1.0f / s;
    }
    __syncthreads();
    for (int i = t; i < 2604; i += 256) ws[WS_AMP + i] = Am[i];
    if (t < PDIM) ws[WS_PROBS + t] = atts[t] * inv_sum;
}

// grid(NCH, BD). Stage -> agg (thread = (d,pp), A scalar + x float4 broadcast)
// -> folded gates -> atomicAdd into h. Last-arriving block per b runs the head
// and writes out[b]. One kernel, no separate head launch.
__global__ __launch_bounds__(256) void fused_kernel(
    const float* __restrict__ x, float* __restrict__ ws,
    float* __restrict__ h, const float* __restrict__ W1,
    const float* __restrict__ b1, const float* __restrict__ w2,
    const float* __restrict__ b2, const float* __restrict__ w3,
    const float* __restrict__ b3, float* __restrict__ out)
{
    __shared__ __align__(16) float sm[SM_N];
    int t = threadIdx.x;
    int b = blockIdx.y;
    int c = blockIdx.x;
    int p0 = c * PC;
    int npp = min(PC, PDIM - p0);

    // ---- stage precomputed state + x slice ----
    for (int i = t; i < 651; i += 256)
        ((float4*)(sm + OFF_AS))[i] = ((const float4*)(ws + WS_AMP))[i];
    sm[OFF_WU + t] = ws[WS_WU + t];
    if (t < 64) sm[OFF_BE + t] = ws[WS_BEFF + t];
    if (t < npp) sm[OFF_PR + t] = ws[WS_PROBS + p0 + t];
    if (t < NND * FIN) {
        int n = t >> 2, f = t & 3;
        const float* xp = &x[((b * NND + n) * FIN + f) * PDIM + p0];
        for (int pp = 0; pp < npp; pp++) sm[OFF_XS + (pp * NND + n) * 4 + f] = xp[pp];
    }
    __syncthreads();

    int e = t & 31, r = t >> 5;
    float wuz[4], wuh[4];
    #pragma unroll
    for (int f = 0; f < 4; f++) {
        wuz[f] = sm[OFF_WU + f * EMB + e];
        wuh[f] = sm[OFF_WU + 128 + f * EMB + e];
    }
    float bez = sm[OFF_BE + e], beh = sm[OFF_BE + 32 + e];

    // ---- agg: thread (d,pp) computes agg[pp][d][0..3] ----
    if (t < NND * PC) {
        int pp = t / NND, d = t - pp * NND;
        if (pp < npp) {
            const float*  Ad = sm + OFF_AS + d * NND;     // scalar, 51-stride (coprime 32)
            const float4* xr = (const float4*)(sm + OFF_XS) + pp * NND;  // broadcast
            float4 acc = make_float4(0.f, 0.f, 0.f, 0.f);
            #pragma unroll 3
            for (int s = 0; s < NND; s++) {
                float a = Ad[s]; float4 xv = xr[s];
                acc.x += a * xv.x; acc.y += a * xv.y;
                acc.z += a * xv.z; acc.w += a * xv.w;
            }
            ((float4*)(sm + OFF_AG))[pp * NND + d] = acc;
        }
    }
    __syncthreads();

    // ---- gates + attention-weighted accumulate ----
    float hacc[7] = {0, 0, 0, 0, 0, 0, 0};
    for (int pp = 0; pp < npp; pp++) {
        float pr = sm[OFF_PR + pp];
        #pragma unroll
        for (int k = 0; k < 7; k++) {
            int d = r + 8 * k;
            if (d < NND) {
                float4 ag = ((const float4*)(sm + OFF_AG))[pp * NND + d];
                float az = bez + ag.x * wuz[0] + ag.y * wuz[1] + ag.z * wuz[2] + ag.w * wuz[3];
                float ah = beh + ag.x * wuh[0] + ag.y * wuh[1] + ag.z * wuh[2] + ag.w * wuh[3];
                float Z  = 1.0f / (1.0f + __expf(-az));
                float Ht = 2.0f / (1.0f + __expf(-2.0f * ah)) - 1.0f;
                hacc[k] += pr * (1.0f - Z) * Ht;
            }
        }
    }
    float* dst = &h[b * NE];
    #pragma unroll
    for (int k = 0; k < 7; k++) {
        int d = r + 8 * k;
        if (d < NND) atomicAdd(&dst[d * EMB + e], hacc[k]);
    }

    // ---- last-block-per-b detection ----
    __syncthreads();   // drains this block's h atomics (vmcnt(0) before barrier)
    if (t == 0) {
        __threadfence();
        int old = atomicAdd((int*)(ws + WS_CNT) + b, 1);
        *(int*)(sm + OFF_FLAG) = (old == NCH - 1);
    }
    __syncthreads();
    if (!*(int*)(sm + OFF_FLAG)) return;

    // ---- head (only the 28th block for this b) ----
    for (int i = t; i < NE; i += 256) {
        float v = __hip_atomic_load(&h[b * NE + i], __ATOMIC_RELAXED,
                                    __HIP_MEMORY_SCOPE_AGENT);  // dodge stale L1
        sm[H_HS + i] = fmaxf(v, 0.0f);
    }
    for (int i = t; i < EMB * EMB; i += 256) sm[H_W1 + i] = W1[i];
    if (t < EMB) { sm[H_B1 + t] = b1[t]; sm[H_W2 + t] = w2[t]; }
    if (t < NND) sm[H_W3 + t] = w3[t];
    __syncthreads();
    float acc = 0.0f;
    for (int i = t; i < NE; i += 256) {
        int d = i >> 5, ee = i & 31;
        float a = sm[H_B1 + ee];
        const float* hr = sm + H_HS + d * EMB;
        #pragma unroll
        for (int k = 0; k < EMB; k++) a += hr[k] * sm[H_W1 + k * EMB + ee];
        a = fmaxf(a, 0.0f);
        acc += sm[H_W3 + d] * sm[H_W2 + ee] * a;
    }
    #pragma unroll
    for (int off = 32; off > 0; off >>= 1) acc += __shfl_down(acc, off);
    if ((t & 63) == 0) sm[H_WS + (t >> 6)] = acc;
    __syncthreads();
    if (t == 0) {
        float s = sm[H_WS] + sm[H_WS + 1] + sm[H_WS + 2] + sm[H_WS + 3];
        float s3 = 0.0f;
        for (int d = 0; d < NND; d++) s3 += sm[H_W3 + d];
        float v = s + b2[0] * s3 + b3[0];
        out[b] = 1.0f / (1.0f + __expf(-v));
    }
}

extern "C" void kernel_launch(void* const* d_in, const int* in_sizes, int n_in,
                              void* d_out, int out_size, void* d_ws, size_t ws_size,
                              hipStream_t stream) {
    const float* x         = (const float*)d_in[0];
    const int*   ei        = (const int*)d_in[1];
    const float* conv_z_w  = (const float*)d_in[2];
    const float* conv_z_b  = (const float*)d_in[3];
    const float* conv_h_w  = (const float*)d_in[6];
    const float* conv_h_b  = (const float*)d_in[7];
    const float* lin_z_w   = (const float*)d_in[8];
    const float* lin_z_b   = (const float*)d_in[9];
    const float* lin_h_w   = (const float*)d_in[12];
    const float* lin_h_b   = (const float*)d_in[13];
    const float* attention = (const float*)d_in[14];
    const float* lin1_w    = (const float*)d_in[15];
    const float* lin1_b    = (const float*)d_in[16];
    const float* lin2_w    = (const float*)d_in[17];
    const float* lin2_b    = (const float*)d_in[18];
    const float* lin3_w    = (const float*)d_in[19];
    const float* lin3_b    = (const float*)d_in[20];

    float* ws = (float*)d_ws;
    float* h  = ws + WS_H;

    hipLaunchKernelGGL(setup_kernel, dim3(8), dim3(256), 0, stream,
                       ei, attention, conv_z_w, conv_z_b, conv_h_w, conv_h_b,
                       lin_z_w, lin_z_b, lin_h_w, lin_h_b, ws);
    hipLaunchKernelGGL(fused_kernel, dim3(NCH, BD), dim3(256), 0, stream,
                       x, ws, h, lin1_w, lin1_b, lin2_w, lin2_b,
                       lin3_w, lin3_b, (float*)d_out);
}

// Round 5
// 131.725 us; speedup vs baseline: 1.0349x; 1.0349x over previous
//
#include <hip/hip_runtime.h>
#include <hip/hip_bf16.h>

#define NND 51
#define FIN 4
#define PDIM 137
#define EMB 32
#define EE 408
#define BD 32
#define PC 5
#define NCH 28            // ceil(137/5)
#define NE (NND*EMB)      // 1632

// ws layout (floats)
#define WS_AMP   0        // Ahat compact [d][s] stride 51, padded to 2604
#define WS_PROBS 2608     // 137 (+pad)
#define WS_WU    2752     // [2][4][32] folded W*U
#define WS_BEFF  3008     // [2][32]  folded b*U + b2
#define WS_CNT   3072     // 32 (unused this round, kept for alignment)
#define WS_H     3104     // [B][N][EMB] accumulator (exact-zeroed by setup)

// main-kernel shared offsets (floats), single union'd buffer
#define OFF_AS   0        // 2604
#define OFF_XS   2604     // 1020 : x[pp][n][f], f contiguous (float4 per (pp,n))
#define OFF_AG   3624     // 1020 : agg[pp][d][f] (float4 per (pp,d))
#define OFF_WU   4644     // 256
#define OFF_BE   4900     // 64
#define OFF_PR   4964     // 8
#define SM_N     4972

// grid(8). Block 0: Ahat + softmax + folded gate mats. Blocks 1-7: zero h+cnt.
__global__ __launch_bounds__(256) void setup_kernel(
    const int* __restrict__ ei, const float* __restrict__ att,
    const float* __restrict__ Wz, const float* __restrict__ bz,
    const float* __restrict__ Wh, const float* __restrict__ bh,
    const float* __restrict__ Uz, const float* __restrict__ bz2,
    const float* __restrict__ Uh, const float* __restrict__ bh2,
    float* __restrict__ ws)
{
    int t = threadIdx.x, blk = blockIdx.x;
    if (blk > 0) {   // zero cnt[32] + h[BD*NE] (16B-aligned, 13064 float4s)
        float4* dst = (float4*)(ws + WS_CNT);
        const int n4 = (32 + BD * NE) / 4;
        float4 z = make_float4(0.f, 0.f, 0.f, 0.f);
        for (int i = (blk - 1) * 256 + t; i < n4; i += 7 * 256) dst[i] = z;
        return;
    }
    __shared__ float deg[NND], dinv[NND];
    __shared__ float Am[2604];
    __shared__ float Us[2][EMB * EMB];
    __shared__ float Ws2[2][FIN * EMB];
    __shared__ float atts[PDIM];
    __shared__ float inv_sum;
    for (int i = t; i < 2604; i += 256) Am[i] = 0.0f;
    if (t < NND) deg[t] = 0.0f;
    for (int i = t; i < EMB * EMB; i += 256) { Us[0][i] = Uz[i]; Us[1][i] = Uh[i]; }
    if (t < FIN * EMB) { Ws2[0][t] = Wz[t]; Ws2[1][t] = Wh[t]; }
    if (t < PDIM) atts[t] = att[t];
    __syncthreads();
    for (int e = t; e < EE; e += 256) atomicAdd(&deg[ei[EE + e]], 1.0f);
    __syncthreads();
    if (t < NND) dinv[t] = rsqrtf(deg[t] + 1.0f);   // +1 self loop
    __syncthreads();
    for (int e = t; e < EE; e += 256) {
        int s = ei[e], d = ei[EE + e];
        atomicAdd(&Am[d * NND + s], dinv[s] * dinv[d]);
    }
    {   // wu[g][f][e]: t encodes (g,f,e), 2*4*32 = 256
        int g = t >> 7, f = (t >> 5) & 3, e = t & 31;
        float a = 0.0f;
        for (int k = 0; k < EMB; k++) a += Ws2[g][f * EMB + k] * Us[g][k * EMB + e];
        ws[WS_WU + t] = a;
    }
    if (t < 64) {   // beff[g][e] = b*U + b2
        int g = t >> 5, e = t & 31;
        const float* bb = g ? bh : bz;
        const float* b2 = g ? bh2 : bz2;
        float a = b2[e];
        for (int k = 0; k < EMB; k++) a += bb[k] * Us[g][k * EMB + e];
        ws[WS_BEFF + t] = a;
    }
    __syncthreads();
    if (t < NND) Am[t * 52] += dinv[t] * dinv[t];   // diag: t*51+t
    if (t == 0) {
        float m = -1e30f;
        for (int p = 0; p < PDIM; p++) m = fmaxf(m, atts[p]);
        float s = 0.0f;
        for (int p = 0; p < PDIM; p++) { float v = __expf(atts[p] - m); atts[p] = v; s += v; }
        inv_sum = 1.0f / s;
    }
    __syncthreads();
    for (int i = t; i < 2604; i += 256) ws[WS_AMP + i] = Am[i];
    if (t < PDIM) ws[WS_PROBS + t] = atts[t] * inv_sum;
}

// grid(NCH, BD). Stage -> agg (thread = (pp,d); A scalar reads stride 19 mod 32
// banks = <=2-way = free, x float4 broadcast) -> folded gates -> atomicAdd h.
// No tail work: head is a separate kernel (fusion measured -3us, R4).
__global__ __launch_bounds__(256) void main_kernel(
    const float* __restrict__ x, const float* __restrict__ ws,
    float* __restrict__ h)
{
    __shared__ __align__(16) float sm[SM_N];
    int t = threadIdx.x;
    int b = blockIdx.y;
    int c = blockIdx.x;
    int p0 = c * PC;
    int npp = min(PC, PDIM - p0);

    // ---- stage precomputed state + x slice ----
    for (int i = t; i < 651; i += 256)
        ((float4*)(sm + OFF_AS))[i] = ((const float4*)(ws + WS_AMP))[i];
    sm[OFF_WU + t] = ws[WS_WU + t];
    if (t < 64) sm[OFF_BE + t] = ws[WS_BEFF + t];
    if (t < npp) sm[OFF_PR + t] = ws[WS_PROBS + p0 + t];
    if (t < NND * FIN) {
        int n = t >> 2, f = t & 3;
        const float* xp = &x[((b * NND + n) * FIN + f) * PDIM + p0];
        for (int pp = 0; pp < npp; pp++) sm[OFF_XS + (pp * NND + n) * 4 + f] = xp[pp];
    }
    __syncthreads();

    int e = t & 31, r = t >> 5;
    float wuz[4], wuh[4];
    #pragma unroll
    for (int f = 0; f < 4; f++) {
        wuz[f] = sm[OFF_WU + f * EMB + e];
        wuh[f] = sm[OFF_WU + 128 + f * EMB + e];
    }
    float bez = sm[OFF_BE + e], beh = sm[OFF_BE + 32 + e];

    // ---- agg: thread (pp,d) computes agg[pp][d][0..3] ----
    if (t < NND * PC) {
        int pp = t / NND, d = t - pp * NND;
        if (pp < npp) {
            const float*  Ad = sm + OFF_AS + d * NND;
            const float4* xr = (const float4*)(sm + OFF_XS) + pp * NND;  // broadcast
            float4 acc = make_float4(0.f, 0.f, 0.f, 0.f);
            #pragma unroll 3
            for (int s = 0; s < NND; s++) {
                float a = Ad[s]; float4 xv = xr[s];
                acc.x += a * xv.x; acc.y += a * xv.y;
                acc.z += a * xv.z; acc.w += a * xv.w;
            }
            ((float4*)(sm + OFF_AG))[pp * NND + d] = acc;
        }
    }
    __syncthreads();

    // ---- gates + attention-weighted accumulate ----
    float hacc[7] = {0, 0, 0, 0, 0, 0, 0};
    for (int pp = 0; pp < npp; pp++) {
        float pr = sm[OFF_PR + pp];
        #pragma unroll
        for (int k = 0; k < 7; k++) {
            int d = r + 8 * k;
            if (d < NND) {
                float4 ag = ((const float4*)(sm + OFF_AG))[pp * NND + d];
                float az = bez + ag.x * wuz[0] + ag.y * wuz[1] + ag.z * wuz[2] + ag.w * wuz[3];
                float ah = beh + ag.x * wuh[0] + ag.y * wuh[1] + ag.z * wuh[2] + ag.w * wuh[3];
                float Z  = 1.0f / (1.0f + __expf(-az));
                float Ht = 2.0f / (1.0f + __expf(-2.0f * ah)) - 1.0f;
                hacc[k] += pr * (1.0f - Z) * Ht;
            }
        }
    }
    float* dst = &h[b * NE];
    #pragma unroll
    for (int k = 0; k < 7; k++) {
        int d = r + 8 * k;
        if (d < NND) atomicAdd(&dst[d * EMB + e], hacc[k]);
    }
}

// grid (BD). relu -> lin1 -> relu -> rank-1 collapsed lin2/lin3 -> sigmoid
__global__ __launch_bounds__(256) void head_kernel(
    const float* __restrict__ h, const float* __restrict__ W1,
    const float* __restrict__ b1, const float* __restrict__ w2,
    const float* __restrict__ b2, const float* __restrict__ w3,
    const float* __restrict__ b3, float* __restrict__ out)
{
    __shared__ float hs[NE];
    __shared__ float W1s[EMB * EMB];
    __shared__ float b1s[EMB], w2s[EMB];
    __shared__ float w3s[NND];
    __shared__ float wsum[4];
    int t = threadIdx.x, b = blockIdx.x;
    for (int i = t; i < NE; i += 256) hs[i] = fmaxf(h[b * NE + i], 0.0f);
    for (int i = t; i < EMB * EMB; i += 256) W1s[i] = W1[i];
    if (t < EMB) { b1s[t] = b1[t]; w2s[t] = w2[t]; }
    if (t < NND) w3s[t] = w3[t];
    __syncthreads();
    float acc = 0.0f;
    for (int i = t; i < NE; i += 256) {
        int d = i >> 5, e = i & 31;
        float a = b1s[e];
        const float* hr = &hs[d * EMB];
        #pragma unroll
        for (int k = 0; k < EMB; k++) a += hr[k] * W1s[k * EMB + e];
        a = fmaxf(a, 0.0f);
        acc += w3s[d] * w2s[e] * a;
    }
    #pragma unroll
    for (int off = 32; off > 0; off >>= 1) acc += __shfl_down(acc, off);
    if ((t & 63) == 0) wsum[t >> 6] = acc;
    __syncthreads();
    if (t == 0) {
        float s = wsum[0] + wsum[1] + wsum[2] + wsum[3];
        float s3 = 0.0f;
        for (int d = 0; d < NND; d++) s3 += w3s[d];
        float v = s + b2[0] * s3 + b3[0];
        out[b] = 1.0f / (1.0f + __expf(-v));
    }
}

extern "C" void kernel_launch(void* const* d_in, const int* in_sizes, int n_in,
                              void* d_out, int out_size, void* d_ws, size_t ws_size,
                              hipStream_t stream) {
    const float* x         = (const float*)d_in[0];
    const int*   ei        = (const int*)d_in[1];
    const float* conv_z_w  = (const float*)d_in[2];
    const float* conv_z_b  = (const float*)d_in[3];
    const float* conv_h_w  = (const float*)d_in[6];
    const float* conv_h_b  = (const float*)d_in[7];
    const float* lin_z_w   = (const float*)d_in[8];
    const float* lin_z_b   = (const float*)d_in[9];
    const float* lin_h_w   = (const float*)d_in[12];
    const float* lin_h_b   = (const float*)d_in[13];
    const float* attention = (const float*)d_in[14];
    const float* lin1_w    = (const float*)d_in[15];
    const float* lin1_b    = (const float*)d_in[16];
    const float* lin2_w    = (const float*)d_in[17];
    const float* lin2_b    = (const float*)d_in[18];
    const float* lin3_w    = (const float*)d_in[19];
    const float* lin3_b    = (const float*)d_in[20];

    float* ws = (float*)d_ws;
    float* h  = ws + WS_H;

    hipLaunchKernelGGL(setup_kernel, dim3(8), dim3(256), 0, stream,
                       ei, attention, conv_z_w, conv_z_b, conv_h_w, conv_h_b,
                       lin_z_w, lin_z_b, lin_h_w, lin_h_b, ws);
    hipLaunchKernelGGL(main_kernel, dim3(NCH, BD), dim3(256), 0, stream,
                       x, ws, h);
    hipLaunchKernelGGL(head_kernel, dim3(BD), dim3(256), 0, stream,
                       h, lin1_w, lin1_b, lin2_w, lin2_b, lin3_w, lin3_b,
                       (float*)d_out);
}